// Round 6
// baseline (317.786 us; speedup 1.0000x reference)
//
#include <hip/hip_runtime.h>
#include <hip/hip_bf16.h>

#define B_  32
#define N_  2048
#define M_  2048
#define D_  128

typedef __attribute__((ext_vector_type(4)))  float f32x4;
typedef __attribute__((ext_vector_type(8)))  short bf16x8;

// log2(e) / sqrt(128): softmax in exp2 domain; folded into Q's bf16 cast.
static constexpr float SCALE2 = 1.4426950408889634f / 11.313708498984761f;

__device__ __forceinline__ unsigned short f2bf(float x) {
  union { float f; unsigned u; } c; c.f = x;
  unsigned u = c.u;
  return (unsigned short)((u + 0x7FFFu + ((u >> 16) & 1u)) >> 16);  // RNE
}

__device__ __forceinline__ unsigned pk2bf(float a, float b) {
  float2 f2; f2.x = a; f2.y = b;
  __hip_bfloat162 h = __float22bfloat162_rn(f2);   // v_cvt_pk_bf16_f32
  union { __hip_bfloat162 h; unsigned u; } c; c.h = h;
  return c.u;
}

// 8 f32 -> bf16x8 with scale, identical op order (mul, then RNE pack) to the
// cast path so colstats' S is bitwise-identical to attn's.
__device__ __forceinline__ bf16x8 pack8(f32x4 lo, f32x4 hi, float s) {
  union { bf16x8 v; unsigned u[4]; } c;
  c.u[0] = pk2bf(lo[0] * s, lo[1] * s);
  c.u[1] = pk2bf(lo[2] * s, lo[3] * s);
  c.u[2] = pk2bf(hi[0] * s, hi[1] * s);
  c.u[3] = pk2bf(hi[2] * s, hi[3] * s);
  return c.v;
}

// register-barrier: make a packed frag opaque so the allocator cannot
// rematerialize it (R4's fused kernel re-derived kf every iteration,
// VGPR_Count 56, 2.5x slowdown). volatile asm can't be duplicated.
__device__ __forceinline__ void pinfrag(bf16x8& f) {
  union { bf16x8 v; unsigned u[4]; } p;
  p.v = f;
  asm volatile("" : "+v"(p.u[0]), "+v"(p.u[1]), "+v"(p.u[2]), "+v"(p.u[3]));
  f = p.v;
}

__device__ __forceinline__ float fexp2(float x) {
#if __has_builtin(__builtin_amdgcn_exp2f)
  return __builtin_amdgcn_exp2f(x);
#else
  float r; asm("v_exp_f32 %0, %1" : "=v"(r) : "v"(x)); return r;
#endif
}
__device__ __forceinline__ float flog2(float x) {
#if __has_builtin(__builtin_amdgcn_logf)
  return __builtin_amdgcn_logf(x);
#else
  float r; asm("v_log_f32 %0, %1" : "=v"(r) : "v"(x)); return r;
#endif
}

// async global->LDS, 16B per lane; LDS dest = wave-uniform base + lane*16
__device__ __forceinline__ void gl2lds16(const void* gp, void* lp) {
  __builtin_amdgcn_global_load_lds(
      (const __attribute__((address_space(1))) unsigned int*)gp,
      (__attribute__((address_space(3))) unsigned int*)lp, 16, 0, 0);
}

// ---------- fused front-end (one dispatch) ----------
// blocks [0,1024):      colstats on RAW f32 Q/K (regs only, kf PINNED)
// blocks [1024,3072):   V transpose f32 -> bf16 Vt
// blocks [3072,19456):  Q cast (SCALE2) / K cast to bf16
// colstats blocks dispatch FIRST (longest pole, exactly 4/CU); cast/transpose
// stream behind them, sharing Q/K f32 lines via L2/L3. colsum zeroed by a
// hipMemsetAsync before this kernel. launch_bounds(256,2): VGPR cap 256 so
// the ~115-reg colstats branch cannot spill; runtime occupancy ~4 waves/SIMD.
__global__ __launch_bounds__(256, 2) void fused2_kernel(
    const float* __restrict__ Q, const float* __restrict__ K,
    const float* __restrict__ V, unsigned short* __restrict__ Qb,
    unsigned short* __restrict__ Kb, unsigned short* __restrict__ Vt,
    float* __restrict__ colsum) {
  const int blk = blockIdx.x;

  if (blk < 1024) {
    // ---- colstats: colsum[b][m] += sum_{n in quarter} 2^(s2[n,m]-16) ----
    // id = x*128 + (4b+y); id%8 == (4b+y)%8: the 8 m-blocks sharing a
    // (b, n-quarter) Q stripe co-reside on one XCD. 64 m/wave, 512 n/block.
    const int x    = blk >> 7;            // m-block 0..7
    const int q    = blk & 127;
    const int b    = q >> 2;
    const int y    = q & 3;               // n-quarter
    const int lane = threadIdx.x & 63;
    const int l15  = lane & 15;
    const int quad = lane >> 4;
    const int mw   = x * 256 + (threadIdx.x >> 6) * 64;
    const int nbase = y * (N_ / 4);

    // B-operand: B[col=m=mw+cg*16+l15][k=quad*8+j (+kc*32)] — from f32 K,
    // packed once, PINNED against remat. 64 VGPRs live for the whole loop.
    bf16x8 kf[4][4];
    #pragma unroll
    for (int cg = 0; cg < 4; ++cg) {
      const float* Kr = K + ((size_t)b * M_ + mw + cg * 16 + l15) * D_ + quad * 8;
      #pragma unroll
      for (int kc = 0; kc < 4; ++kc) {
        f32x4 lo = *reinterpret_cast<const f32x4*>(Kr + kc * 32);
        f32x4 hi = *reinterpret_cast<const f32x4*>(Kr + kc * 32 + 4);
        kf[cg][kc] = pack8(lo, hi, 1.0f);
        pinfrag(kf[cg][kc]);
      }
    }

    // A-operand rows: A[row=n=ng*16+l15][k=quad*8+j (+kc*32)] — from f32 Q
    const float* Qr = Q + ((size_t)b * N_ + nbase + l15) * D_ + quad * 8;

    float psum[4] = {0.f, 0.f, 0.f, 0.f};
    for (int ng = 0; ng < 32; ++ng) {
      const float* qp = Qr + (size_t)ng * (16 * D_);
      bf16x8 af[4];
      #pragma unroll
      for (int kc = 0; kc < 4; ++kc) {
        f32x4 lo = *reinterpret_cast<const f32x4*>(qp + kc * 32);
        f32x4 hi = *reinterpret_cast<const f32x4*>(qp + kc * 32 + 4);
        af[kc] = pack8(lo, hi, SCALE2);
      }
      f32x4 acc[4] = {{0.f,0.f,0.f,0.f}, {0.f,0.f,0.f,0.f},
                      {0.f,0.f,0.f,0.f}, {0.f,0.f,0.f,0.f}};
      __builtin_amdgcn_s_setprio(1);
      #pragma unroll
      for (int kc = 0; kc < 4; ++kc)
        #pragma unroll
        for (int cg = 0; cg < 4; ++cg)
          acc[cg] = __builtin_amdgcn_mfma_f32_16x16x32_bf16(
              af[kc], kf[cg][kc], acc[cg], 0, 0, 0);
      __builtin_amdgcn_s_setprio(0);
      #pragma unroll
      for (int cg = 0; cg < 4; ++cg)
        psum[cg] += fexp2(acc[cg][0] - 16.f) + fexp2(acc[cg][1] - 16.f) +
                    fexp2(acc[cg][2] - 16.f) + fexp2(acc[cg][3] - 16.f);
    }
    // rows n live across quad+regs: reduce over quad; m columns at quad==0
    #pragma unroll
    for (int cg = 0; cg < 4; ++cg) {
      psum[cg] += __shfl_xor(psum[cg], 16);
      psum[cg] += __shfl_xor(psum[cg], 32);
    }
    if (quad == 0) {
      #pragma unroll
      for (int cg = 0; cg < 4; ++cg)
        atomicAdd(colsum + (size_t)b * M_ + mw + cg * 16 + l15, psum[cg]);
    }
    return;
  }

  if (blk < 3072) {
    // ---- V transpose: idx -> (b, m0, d0); 2048 blocks = 32 x 2 x 32 ----
    const int idx = blk - 1024;
    const int b  = idx >> 6;
    const int m0 = ((idx >> 1) & 31) * 64;
    const int d0 = (idx & 1) * 64;
    __shared__ float t[64][65];
    const int tid = threadIdx.x;
    const int r = tid >> 2;   // 0..63
    const int c = tid & 3;    // 0..3
    const float* src = V + ((size_t)b * M_ + (m0 + r)) * D_ + d0 + c * 16;
    #pragma unroll
    for (int i = 0; i < 4; ++i) {
      float4 v = reinterpret_cast<const float4*>(src)[i];
      t[r][c * 16 + i * 4 + 0] = v.x;
      t[r][c * 16 + i * 4 + 1] = v.y;
      t[r][c * 16 + i * 4 + 2] = v.z;
      t[r][c * 16 + i * 4 + 3] = v.w;
    }
    __syncthreads();
    ushort4 ob[4];
    #pragma unroll
    for (int i = 0; i < 4; ++i) {
      ob[i].x = f2bf(t[c * 16 + i * 4 + 0][r]);
      ob[i].y = f2bf(t[c * 16 + i * 4 + 1][r]);
      ob[i].z = f2bf(t[c * 16 + i * 4 + 2][r]);
      ob[i].w = f2bf(t[c * 16 + i * 4 + 3][r]);
    }
    ushort4* dst = reinterpret_cast<ushort4*>(
        Vt + ((size_t)b * D_ + d0 + r) * M_ + m0 + c * 16);
    #pragma unroll
    for (int i = 0; i < 4; ++i) dst[i] = ob[i];
    return;
  }

  // ---- Q/K casts: 16B load / 8B store per thread ----
  const int r2 = blk - 3072;
  const bool isK = r2 >= 8192;
  const int i = (isK ? r2 - 8192 : r2) * 256 + threadIdx.x;  // float4 idx < 2^21
  const float4* src = reinterpret_cast<const float4*>(isK ? K : Q);
  uint2* dst = reinterpret_cast<uint2*>(isK ? Kb : Qb);
  const float sc = isK ? 1.0f : SCALE2;
  const float4 v = src[i];
  uint2 o;
  o.x = pk2bf(v.x * sc, v.y * sc);
  o.y = pk2bf(v.z * sc, v.w * sc);
  dst[i] = o;
}

// ---------- pass 2: O[n,d] = sum_m 2^(s2[n,m]-cml[m]) * Vt[d,m] ----------
// VERBATIM v9 (proven 87.9us, MfmaUtil 33%, FETCH 24.7MB). 512 blocks,
// XCD-swizzled (id%8==b%8). 64-m chunks, double-buffered K/V LDS, 2-phase
// schedule, one barrier per chunk, setprio around MFMA clusters.
__global__ __launch_bounds__(256, 2) void attn_v9_kernel(
    const unsigned short* __restrict__ Qb, const unsigned short* __restrict__ Kb,
    const unsigned short* __restrict__ Vt, const float* __restrict__ colsum,
    float* __restrict__ out) {
  const int id   = blockIdx.x;        // 0..511
  const int b    = id & 31;
  const int xq   = id >> 5;           // n-block 0..15
  const int wv   = threadIdx.x >> 6;  // 0..3
  const int lane = threadIdx.x & 63;
  const int l15  = lane & 15;
  const int quad = lane >> 4;
  const int nq   = xq * 128 + wv * 32;

  __shared__ unsigned short kbuf[2][64 * 128];  // 2x16 KB: rows m (256B), chunk c^(m&15)
  __shared__ unsigned short vbuf[2][128 * 64];  // 2x16 KB: rows d (128B), chunk c^(d&7)
  __shared__ unsigned short pbuf[4][32 * 40];   // 10 KB: per-wave P^T [n][m32], stride 80B
  __shared__ float cmlb[2][64];                 // per-chunk log2 column denominators

  // Q B-operand: B[col=n=ng*16+l15][k=quad*8+j (+kc*32)] — loop invariant
  bf16x8 qf[2][4];
  #pragma unroll
  for (int ng = 0; ng < 2; ++ng) {
    const unsigned short* Qr =
        Qb + ((size_t)b * N_ + nq + ng * 16 + l15) * D_ + quad * 8;
    #pragma unroll
    for (int kc = 0; kc < 4; ++kc)
      qf[ng][kc] = *reinterpret_cast<const bf16x8*>(Qr + kc * 32);
  }

  // hoisted LDS bases (u16 units)
  const unsigned short* pk[4];   // K read: + cb*8192 + sub*4096 + cg*2048
  #pragma unroll
  for (int kc = 0; kc < 4; ++kc)
    pk[kc] = kbuf[0] + l15 * 128 + (((kc * 4 + quad) ^ l15) * 8);
  const unsigned short* pv[2];   // V read: + cb*8192 + dt*1024
  #pragma unroll
  for (int sub = 0; sub < 2; ++sub)
    pv[sub] = vbuf[0] + l15 * 64 + (((sub * 4 + quad) ^ (l15 & 7)) * 8);
  unsigned short* pww[2];        // P write: + cg*16
  const unsigned short* pwr[2];  // P read
  #pragma unroll
  for (int ng = 0; ng < 2; ++ng) {
    pww[ng] = pbuf[wv] + (ng * 16 + l15) * 40 + quad * 4;
    pwr[ng] = pbuf[wv] + (ng * 16 + l15) * 40 + quad * 8;
  }

  // running DMA source ptrs (4 K + 4 V slots/thread), constant LDS dests
  const unsigned short* kg[4]; unsigned short* kl[4];
  const unsigned short* vg[4]; unsigned short* vl[4];
  #pragma unroll
  for (int i = 0; i < 4; ++i) {
    int s = i * 256 + threadIdx.x;               // 16B slot 0..1023
    int rk = s >> 4, ck = (s & 15) ^ (rk & 15);
    kg[i] = Kb + ((size_t)b * M_ + rk) * D_ + ck * 8;
    kl[i] = kbuf[0] + (size_t)s * 8;
    int rv = s >> 3, cv = (s & 7) ^ (rv & 7);
    vg[i] = Vt + ((size_t)b * D_ + rv) * M_ + cv * 8;
    vl[i] = vbuf[0] + (size_t)s * 8;
  }

  const float* csb = colsum + (size_t)b * M_;

  f32x4 o[2][8];
  #pragma unroll
  for (int ng = 0; ng < 2; ++ng)
    #pragma unroll
    for (int dt = 0; dt < 8; ++dt) o[ng][dt] = (f32x4){0.f, 0.f, 0.f, 0.f};

#define AT_STAGE(nb, chunk)                                                   \
  { _Pragma("unroll")                                                         \
    for (int i = 0; i < 4; ++i) {                                             \
      gl2lds16(kg[i], kl[i] + (nb) * (64 * 128));                             \
      kg[i] += 64 * D_;                                                       \
      gl2lds16(vg[i], vl[i] + (nb) * (128 * 64));                             \
      vg[i] += 64;                                                            \
    }                                                                         \
    if (threadIdx.x < 64)                                                     \
      cmlb[nb][threadIdx.x] =                                                 \
          flog2(csb[(chunk) * 64 + threadIdx.x]) + 16.f; }

#define AT_COMPUTE(cb)                                                        \
  { _Pragma("unroll")                                                         \
    for (int sub = 0; sub < 2; ++sub) {                                       \
      /* QK^T (S^T): sacc[cg][ng]: row m=sub*32+cg*16+quad*4+r, col n */      \
      f32x4 sacc[2][2] = {{{0.f,0.f,0.f,0.f},{0.f,0.f,0.f,0.f}},              \
                          {{0.f,0.f,0.f,0.f},{0.f,0.f,0.f,0.f}}};             \
      __builtin_amdgcn_s_setprio(1);                                          \
      _Pragma("unroll")                                                       \
      for (int kc = 0; kc < 4; ++kc) {                                        \
        _Pragma("unroll")                                                     \
        for (int cg = 0; cg < 2; ++cg) {                                      \
          bf16x8 kfr = *reinterpret_cast<const bf16x8*>(                      \
              pk[kc] + (cb) * (64 * 128) + sub * 4096 + cg * 2048);           \
          sacc[cg][0] = __builtin_amdgcn_mfma_f32_16x16x32_bf16(              \
              kfr, qf[0][kc], sacc[cg][0], 0, 0, 0);                          \
          sacc[cg][1] = __builtin_amdgcn_mfma_f32_16x16x32_bf16(              \
              kfr, qf[1][kc], sacc[cg][1], 0, 0, 0);                          \
        }                                                                     \
      }                                                                       \
      __builtin_amdgcn_s_setprio(0);                                          \
      /* normalized P: w = 2^(s2 - cml[m]); packed b64 of 4 consecutive m */  \
      _Pragma("unroll")                                                       \
      for (int cg = 0; cg < 2; ++cg) {                                        \
        float4 cm4 = *reinterpret_cast<const float4*>(                        \
            &cmlb[cb][sub * 32 + cg * 16 + quad * 4]);                        \
        _Pragma("unroll")                                                     \
        for (int ng = 0; ng < 2; ++ng) {                                      \
          uint2 w;                                                            \
          w.x = pk2bf(fexp2(sacc[cg][ng][0] - cm4.x),                         \
                      fexp2(sacc[cg][ng][1] - cm4.y));                        \
          w.y = pk2bf(fexp2(sacc[cg][ng][2] - cm4.z),                         \
                      fexp2(sacc[cg][ng][3] - cm4.w));                        \
          *reinterpret_cast<uint2*>(pww[ng] + cg * 16) = w;                   \
        }                                                                     \
      }                                                                       \
      /* P A-frags (same-wave LDS RAW; lgkmcnt ordered) */                    \
      bf16x8 pa0 = *reinterpret_cast<const bf16x8*>(pwr[0]);                  \
      bf16x8 pa1 = *reinterpret_cast<const bf16x8*>(pwr[1]);                  \
      __builtin_amdgcn_s_setprio(1);                                          \
      _Pragma("unroll")                                                       \
      for (int dt = 0; dt < 8; ++dt) {                                        \
        bf16x8 vfr = *reinterpret_cast<const bf16x8*>(                        \
            pv[sub] + (cb) * (128 * 64) + dt * 1024);                         \
        o[0][dt] = __builtin_amdgcn_mfma_f32_16x16x32_bf16(                   \
            pa0, vfr, o[0][dt], 0, 0, 0);                                     \
        o[1][dt] = __builtin_amdgcn_mfma_f32_16x16x32_bf16(                   \
            pa1, vfr, o[1][dt], 0, 0, 0);                                     \
      }                                                                       \
      __builtin_amdgcn_s_setprio(0);                                          \
    } }

  AT_STAGE(0, 0);
  __syncthreads();
  #pragma unroll 1
  for (int it = 0; it < 32; it += 2) {
    AT_STAGE(1, it + 1);                       // prefetch while computing cur
    AT_COMPUTE(0);
    __syncthreads();                           // next chunk landed; buf0 free
    if (it + 2 < 32) AT_STAGE(0, it + 2);
    AT_COMPUTE(1);
    __syncthreads();
  }
#undef AT_STAGE
#undef AT_COMPUTE

  // epilogue: o[ng][dt][r] = O[nq + ng*16 + quad*4 + r][dt*16 + l15]
  #pragma unroll
  for (int ng = 0; ng < 2; ++ng)
    #pragma unroll
    for (int dt = 0; dt < 8; ++dt)
      #pragma unroll
      for (int r = 0; r < 4; ++r)
        out[((size_t)b * N_ + nq + ng * 16 + quad * 4 + r) * D_ + dt * 16 + l15] =
            o[ng][dt][r];
}

extern "C" void kernel_launch(void* const* d_in, const int* in_sizes, int n_in,
                              void* d_out, int out_size, void* d_ws, size_t ws_size,
                              hipStream_t stream) {
  const float* Q = (const float*)d_in[0];
  const float* K = (const float*)d_in[1];
  const float* V = (const float*)d_in[2];
  float* out = (float*)d_out;

  const size_t elems = (size_t)B_ * N_ * D_;   // 8,388,608 per tensor
  unsigned short* Qb = (unsigned short*)d_ws;                  // 16 MB
  unsigned short* Kb = Qb + elems;                             // 16 MB
  unsigned short* Vt = Kb + elems;                             // 16 MB
  float* colsum = (float*)(Vt + elems);                        // 256 KB
  // total ws use ~= 48.3 MB (proven safe)

  hipMemsetAsync(colsum, 0, (size_t)B_ * M_ * sizeof(float), stream);
  fused2_kernel<<<19456, 256, 0, stream>>>(Q, K, V, Qb, Kb, Vt, colsum);
  attn_v9_kernel<<<512, 256, 0, stream>>>(Qb, Kb, Vt, colsum, out);
}

// Round 7
// 282.934 us; speedup vs baseline: 1.1232x; 1.1232x over previous
//
#include <hip/hip_runtime.h>
#include <hip/hip_bf16.h>

#define B_  32
#define N_  2048
#define M_  2048
#define D_  128

typedef __attribute__((ext_vector_type(4)))  float f32x4;
typedef __attribute__((ext_vector_type(8)))  short bf16x8;

// log2(e) / sqrt(128): softmax in exp2 domain; folded into Q's bf16 cast.
static constexpr float SCALE2 = 1.4426950408889634f / 11.313708498984761f;

__device__ __forceinline__ unsigned short f2bf(float x) {
  union { float f; unsigned u; } c; c.f = x;
  unsigned u = c.u;
  return (unsigned short)((u + 0x7FFFu + ((u >> 16) & 1u)) >> 16);  // RNE
}

__device__ __forceinline__ unsigned pk2bf(float a, float b) {
  float2 f2; f2.x = a; f2.y = b;
  __hip_bfloat162 h = __float22bfloat162_rn(f2);   // v_cvt_pk_bf16_f32
  union { __hip_bfloat162 h; unsigned u; } c; c.h = h;
  return c.u;
}

__device__ __forceinline__ float fexp2(float x) {
#if __has_builtin(__builtin_amdgcn_exp2f)
  return __builtin_amdgcn_exp2f(x);
#else
  float r; asm("v_exp_f32 %0, %1" : "=v"(r) : "v"(x)); return r;
#endif
}
__device__ __forceinline__ float flog2(float x) {
#if __has_builtin(__builtin_amdgcn_logf)
  return __builtin_amdgcn_logf(x);
#else
  float r; asm("v_log_f32 %0, %1" : "=v"(r) : "v"(x)); return r;
#endif
}

// async global->LDS, 16B per lane; LDS dest = wave-uniform base + lane*16
__device__ __forceinline__ void gl2lds16(const void* gp, void* lp) {
  __builtin_amdgcn_global_load_lds(
      (const __attribute__((address_space(1))) unsigned int*)gp,
      (__attribute__((address_space(3))) unsigned int*)lp, 16, 0, 0);
}

// ---------- prep (one dispatch): V transpose FIRST, then cast Q (SCALE2),
// cast K, zero colsum. VERBATIM R3 (proven; part of a 238.7us total).
// blocks [0,2048): V transpose; [2048,10240): Q cast; [10240,18432): K cast.
__global__ __launch_bounds__(256) void prep_kernel(
    const float* __restrict__ Q, const float* __restrict__ K,
    const float* __restrict__ V, unsigned short* __restrict__ Qb,
    unsigned short* __restrict__ Kb, unsigned short* __restrict__ Vt,
    float* __restrict__ colsum) {
  const int blk = blockIdx.x;
  if (blk >= 2048) {
    const bool isK = blk >= 10240;
    const int i = (isK ? blk - 10240 : blk - 2048) * 256 + threadIdx.x;
    if (!isK && blk - 2048 < 64) {
      const int j = (blk - 2048) * 256 + threadIdx.x;   // < 16384 == B_*M_/4
      reinterpret_cast<float4*>(colsum)[j] = make_float4(0.f, 0.f, 0.f, 0.f);
    }
    const float4* src = reinterpret_cast<const float4*>(isK ? K : Q);
    uint2* dst = reinterpret_cast<uint2*>(isK ? Kb : Qb);
    const float sc = isK ? 1.0f : SCALE2;
    const float4 v = src[i];
    uint2 o;
    o.x = pk2bf(v.x * sc, v.y * sc);
    o.y = pk2bf(v.z * sc, v.w * sc);
    dst[i] = o;
    return;
  }
  // V transpose: idx -> (b, m0, d0); 2048 blocks = (M/64=32) x (D/64=2) x (B=32)
  const int idx = blk;
  const int b  = idx >> 6;
  const int m0 = ((idx >> 1) & 31) * 64;
  const int d0 = (idx & 1) * 64;
  __shared__ float t[64][65];
  const int tid = threadIdx.x;
  const int r = tid >> 2;   // 0..63
  const int c = tid & 3;    // 0..3
  const float* src = V + ((size_t)b * M_ + (m0 + r)) * D_ + d0 + c * 16;
  #pragma unroll
  for (int i = 0; i < 4; ++i) {
    float4 v = reinterpret_cast<const float4*>(src)[i];
    t[r][c * 16 + i * 4 + 0] = v.x;
    t[r][c * 16 + i * 4 + 1] = v.y;
    t[r][c * 16 + i * 4 + 2] = v.z;
    t[r][c * 16 + i * 4 + 3] = v.w;
  }
  __syncthreads();
  ushort4 ob[4];
  #pragma unroll
  for (int i = 0; i < 4; ++i) {
    ob[i].x = f2bf(t[c * 16 + i * 4 + 0][r]);
    ob[i].y = f2bf(t[c * 16 + i * 4 + 1][r]);
    ob[i].z = f2bf(t[c * 16 + i * 4 + 2][r]);
    ob[i].w = f2bf(t[c * 16 + i * 4 + 3][r]);
  }
  ushort4* dst = reinterpret_cast<ushort4*>(
      Vt + ((size_t)b * D_ + d0 + r) * M_ + m0 + c * 16);
  #pragma unroll
  for (int i = 0; i < 4; ++i) dst[i] = ob[i];
}

// ---------- pass 1: colsum[b][m] += sum_n 2^(s2[n,m]-16) ----------
// attn_v9 CLONE: identical grid (512, id%8==b%8 XCD swizzle), identical
// Q-frags-in-regs + double-buffered K staging + QK^T macro. Softmax/PV
// replaced by: exp2(sacc-16) -> ng-sum -> shfl_xor butterfly over l15 (the n
// axis, lane bits 0..3) -> ONE plain LDS store per (chunk,sub) into a
// per-wave slice[2048] (each m written exactly once: no rmw, no zero-init).
// Epilogue: sum 4 slices, 8 atomicAdds/thread. LDS 64KB -> 2 blocks/CU.
// Rationale: attn_v9 is MEASURED at 88us doing a strict superset of this
// per-chunk work (2x MFMA + softmax + P roundtrip + V staging).
__global__ __launch_bounds__(256, 2) void colstats_v10_kernel(
    const unsigned short* __restrict__ Qb, const unsigned short* __restrict__ Kb,
    float* __restrict__ colsum) {
  const int id   = blockIdx.x;        // 0..511
  const int b    = id & 31;
  const int xq   = id >> 5;           // n-block 0..15
  const int wv   = threadIdx.x >> 6;  // 0..3
  const int lane = threadIdx.x & 63;
  const int l15  = lane & 15;
  const int quad = lane >> 4;
  const int nq   = xq * 128 + wv * 32;

  __shared__ unsigned short kbuf[2][64 * 128];  // 2x16 KB: rows m, chunk c^(m&15)
  __shared__ float pslice[4][2048];             // 32 KB: per-wave column partials

  // Q B-operand: B[col=n=ng*16+l15][k=quad*8+j (+kc*32)] — loop invariant
  bf16x8 qf[2][4];
  #pragma unroll
  for (int ng = 0; ng < 2; ++ng) {
    const unsigned short* Qr =
        Qb + ((size_t)b * N_ + nq + ng * 16 + l15) * D_ + quad * 8;
    #pragma unroll
    for (int kc = 0; kc < 4; ++kc)
      qf[ng][kc] = *reinterpret_cast<const bf16x8*>(Qr + kc * 32);
  }

  // hoisted LDS bases (u16 units): K read: + cb*8192 + sub*4096 + cg*2048
  const unsigned short* pk[4];
  #pragma unroll
  for (int kc = 0; kc < 4; ++kc)
    pk[kc] = kbuf[0] + l15 * 128 + (((kc * 4 + quad) ^ l15) * 8);

  // running DMA source ptrs (4 K slots/thread), constant LDS dests
  const unsigned short* kg[4]; unsigned short* kl[4];
  #pragma unroll
  for (int i = 0; i < 4; ++i) {
    int s = i * 256 + threadIdx.x;               // 16B slot 0..1023
    int rk = s >> 4, ck = (s & 15) ^ (rk & 15);
    kg[i] = Kb + ((size_t)b * M_ + rk) * D_ + ck * 8;
    kl[i] = kbuf[0] + (size_t)s * 8;
  }

  float* myslice = pslice[wv];

#define CS_STAGE(nb)                                                          \
  { _Pragma("unroll")                                                         \
    for (int i = 0; i < 4; ++i) {                                             \
      gl2lds16(kg[i], kl[i] + (nb) * (64 * 128));                             \
      kg[i] += 64 * D_;                                                       \
    } }

#define CS_COMPUTE(cb, chunk)                                                 \
  { _Pragma("unroll")                                                         \
    for (int sub = 0; sub < 2; ++sub) {                                       \
      /* QK^T (S^T): sacc[cg][ng]: row m=chunk*64+sub*32+cg*16+quad*4+r, */   \
      /* col n = nq + ng*16 + l15 — VERBATIM attn_v9 QK^T block */            \
      f32x4 sacc[2][2] = {{{0.f,0.f,0.f,0.f},{0.f,0.f,0.f,0.f}},              \
                          {{0.f,0.f,0.f,0.f},{0.f,0.f,0.f,0.f}}};             \
      __builtin_amdgcn_s_setprio(1);                                          \
      _Pragma("unroll")                                                       \
      for (int kc = 0; kc < 4; ++kc) {                                        \
        _Pragma("unroll")                                                     \
        for (int cg = 0; cg < 2; ++cg) {                                      \
          bf16x8 kfr = *reinterpret_cast<const bf16x8*>(                      \
              pk[kc] + (cb) * (64 * 128) + sub * 4096 + cg * 2048);           \
          sacc[cg][0] = __builtin_amdgcn_mfma_f32_16x16x32_bf16(              \
              kfr, qf[0][kc], sacc[cg][0], 0, 0, 0);                          \
          sacc[cg][1] = __builtin_amdgcn_mfma_f32_16x16x32_bf16(              \
              kfr, qf[1][kc], sacc[cg][1], 0, 0, 0);                          \
        }                                                                     \
      }                                                                       \
      __builtin_amdgcn_s_setprio(0);                                          \
      /* exp2 + ng-sum: pe[cg][r], then butterfly-sum over l15 (n axis) */    \
      float pe0[4], pe1[4];                                                   \
      _Pragma("unroll")                                                       \
      for (int r = 0; r < 4; ++r) {                                           \
        pe0[r] = fexp2(sacc[0][0][r] - 16.f) + fexp2(sacc[0][1][r] - 16.f);   \
        pe1[r] = fexp2(sacc[1][0][r] - 16.f) + fexp2(sacc[1][1][r] - 16.f);   \
      }                                                                       \
      _Pragma("unroll")                                                       \
      for (int r = 0; r < 4; ++r) {                                           \
        pe0[r] += __shfl_xor(pe0[r], 1);  pe1[r] += __shfl_xor(pe1[r], 1);    \
        pe0[r] += __shfl_xor(pe0[r], 2);  pe1[r] += __shfl_xor(pe1[r], 2);    \
        pe0[r] += __shfl_xor(pe0[r], 4);  pe1[r] += __shfl_xor(pe1[r], 4);    \
        pe0[r] += __shfl_xor(pe0[r], 8);  pe1[r] += __shfl_xor(pe1[r], 8);    \
      }                                                                       \
      /* each m hit exactly once per block: plain stores, no rmw */           \
      if (l15 == 0) {                                                         \
        float* pw = myslice + (chunk) * 64 + sub * 32 + quad * 4;             \
        _Pragma("unroll")                                                     \
        for (int r = 0; r < 4; ++r) {                                         \
          pw[r]      = pe0[r];                                                \
          pw[16 + r] = pe1[r];                                                \
        }                                                                     \
      }                                                                       \
    } }

  CS_STAGE(0);                                 // chunk 0
  __syncthreads();
  #pragma unroll 1
  for (int it = 0; it < 32; it += 2) {
    CS_STAGE(1);                               // prefetch while computing cur
    CS_COMPUTE(0, it);
    __syncthreads();                           // next chunk landed; buf0 free
    if (it + 2 < 32) CS_STAGE(0);
    CS_COMPUTE(1, it + 1);
    __syncthreads();
  }
#undef CS_STAGE
#undef CS_COMPUTE

  // epilogue: sum the 4 wave slices, one atomic per m (16 blocks contend)
  const int tid = threadIdx.x;
  #pragma unroll
  for (int j = 0; j < 8; ++j) {
    const int m = j * 256 + tid;
    const float s = pslice[0][m] + pslice[1][m] + pslice[2][m] + pslice[3][m];
    atomicAdd(colsum + (size_t)b * M_ + m, s);
  }
}

// ---------- pass 2: O[n,d] = sum_m 2^(s2[n,m]-cml[m]) * Vt[d,m] ----------
// VERBATIM v9 (proven 87.9us, MfmaUtil 33%, FETCH 24.7MB). 512 blocks,
// XCD-swizzled (id%8==b%8). 64-m chunks, double-buffered K/V LDS, 2-phase
// schedule, one barrier per chunk, setprio around MFMA clusters.
__global__ __launch_bounds__(256, 2) void attn_v9_kernel(
    const unsigned short* __restrict__ Qb, const unsigned short* __restrict__ Kb,
    const unsigned short* __restrict__ Vt, const float* __restrict__ colsum,
    float* __restrict__ out) {
  const int id   = blockIdx.x;        // 0..511
  const int b    = id & 31;
  const int xq   = id >> 5;           // n-block 0..15
  const int wv   = threadIdx.x >> 6;  // 0..3
  const int lane = threadIdx.x & 63;
  const int l15  = lane & 15;
  const int quad = lane >> 4;
  const int nq   = xq * 128 + wv * 32;

  __shared__ unsigned short kbuf[2][64 * 128];  // 2x16 KB: rows m (256B), chunk c^(m&15)
  __shared__ unsigned short vbuf[2][128 * 64];  // 2x16 KB: rows d (128B), chunk c^(d&7)
  __shared__ unsigned short pbuf[4][32 * 40];   // 10 KB: per-wave P^T [n][m32], stride 80B
  __shared__ float cmlb[2][64];                 // per-chunk log2 column denominators

  // Q B-operand: B[col=n=ng*16+l15][k=quad*8+j (+kc*32)] — loop invariant
  bf16x8 qf[2][4];
  #pragma unroll
  for (int ng = 0; ng < 2; ++ng) {
    const unsigned short* Qr =
        Qb + ((size_t)b * N_ + nq + ng * 16 + l15) * D_ + quad * 8;
    #pragma unroll
    for (int kc = 0; kc < 4; ++kc)
      qf[ng][kc] = *reinterpret_cast<const bf16x8*>(Qr + kc * 32);
  }

  // hoisted LDS bases (u16 units)
  const unsigned short* pk[4];   // K read: + cb*8192 + sub*4096 + cg*2048
  #pragma unroll
  for (int kc = 0; kc < 4; ++kc)
    pk[kc] = kbuf[0] + l15 * 128 + (((kc * 4 + quad) ^ l15) * 8);
  const unsigned short* pv[2];   // V read: + cb*8192 + dt*1024
  #pragma unroll
  for (int sub = 0; sub < 2; ++sub)
    pv[sub] = vbuf[0] + l15 * 64 + (((sub * 4 + quad) ^ (l15 & 7)) * 8);
  unsigned short* pww[2];        // P write: + cg*16
  const unsigned short* pwr[2];  // P read
  #pragma unroll
  for (int ng = 0; ng < 2; ++ng) {
    pww[ng] = pbuf[wv] + (ng * 16 + l15) * 40 + quad * 4;
    pwr[ng] = pbuf[wv] + (ng * 16 + l15) * 40 + quad * 8;
  }

  // running DMA source ptrs (4 K + 4 V slots/thread), constant LDS dests
  const unsigned short* kg[4]; unsigned short* kl[4];
  const unsigned short* vg[4]; unsigned short* vl[4];
  #pragma unroll
  for (int i = 0; i < 4; ++i) {
    int s = i * 256 + threadIdx.x;               // 16B slot 0..1023
    int rk = s >> 4, ck = (s & 15) ^ (rk & 15);
    kg[i] = Kb + ((size_t)b * M_ + rk) * D_ + ck * 8;
    kl[i] = kbuf[0] + (size_t)s * 8;
    int rv = s >> 3, cv = (s & 7) ^ (rv & 7);
    vg[i] = Vt + ((size_t)b * D_ + rv) * M_ + cv * 8;
    vl[i] = vbuf[0] + (size_t)s * 8;
  }

  const float* csb = colsum + (size_t)b * M_;

  f32x4 o[2][8];
  #pragma unroll
  for (int ng = 0; ng < 2; ++ng)
    #pragma unroll
    for (int dt = 0; dt < 8; ++dt) o[ng][dt] = (f32x4){0.f, 0.f, 0.f, 0.f};

#define AT_STAGE(nb, chunk)                                                   \
  { _Pragma("unroll")                                                         \
    for (int i = 0; i < 4; ++i) {                                             \
      gl2lds16(kg[i], kl[i] + (nb) * (64 * 128));                             \
      kg[i] += 64 * D_;                                                       \
      gl2lds16(vg[i], vl[i] + (nb) * (128 * 64));                             \
      vg[i] += 64;                                                            \
    }                                                                         \
    if (threadIdx.x < 64)                                                     \
      cmlb[nb][threadIdx.x] =                                                 \
          flog2(csb[(chunk) * 64 + threadIdx.x]) + 16.f; }

#define AT_COMPUTE(cb)                                                        \
  { _Pragma("unroll")                                                         \
    for (int sub = 0; sub < 2; ++sub) {                                       \
      /* QK^T (S^T): sacc[cg][ng]: row m=sub*32+cg*16+quad*4+r, col n */      \
      f32x4 sacc[2][2] = {{{0.f,0.f,0.f,0.f},{0.f,0.f,0.f,0.f}},              \
                          {{0.f,0.f,0.f,0.f},{0.f,0.f,0.f,0.f}}};             \
      __builtin_amdgcn_s_setprio(1);                                          \
      _Pragma("unroll")                                                       \
      for (int kc = 0; kc < 4; ++kc) {                                        \
        _Pragma("unroll")                                                     \
        for (int cg = 0; cg < 2; ++cg) {                                      \
          bf16x8 kfr = *reinterpret_cast<const bf16x8*>(                      \
              pk[kc] + (cb) * (64 * 128) + sub * 4096 + cg * 2048);           \
          sacc[cg][0] = __builtin_amdgcn_mfma_f32_16x16x32_bf16(              \
              kfr, qf[0][kc], sacc[cg][0], 0, 0, 0);                          \
          sacc[cg][1] = __builtin_amdgcn_mfma_f32_16x16x32_bf16(              \
              kfr, qf[1][kc], sacc[cg][1], 0, 0, 0);                          \
        }                                                                     \
      }                                                                       \
      __builtin_amdgcn_s_setprio(0);                                          \
      /* normalized P: w = 2^(s2 - cml[m]); packed b64 of 4 consecutive m */  \
      _Pragma("unroll")                                                       \
      for (int cg = 0; cg < 2; ++cg) {                                        \
        float4 cm4 = *reinterpret_cast<const float4*>(                        \
            &cmlb[cb][sub * 32 + cg * 16 + quad * 4]);                        \
        _Pragma("unroll")                                                     \
        for (int ng = 0; ng < 2; ++ng) {                                      \
          uint2 w;                                                            \
          w.x = pk2bf(fexp2(sacc[cg][ng][0] - cm4.x),                         \
                      fexp2(sacc[cg][ng][1] - cm4.y));                        \
          w.y = pk2bf(fexp2(sacc[cg][ng][2] - cm4.z),                         \
                      fexp2(sacc[cg][ng][3] - cm4.w));                        \
          *reinterpret_cast<uint2*>(pww[ng] + cg * 16) = w;                   \
        }                                                                     \
      }                                                                       \
      /* P A-frags (same-wave LDS RAW; lgkmcnt ordered) */                    \
      bf16x8 pa0 = *reinterpret_cast<const bf16x8*>(pwr[0]);                  \
      bf16x8 pa1 = *reinterpret_cast<const bf16x8*>(pwr[1]);                  \
      __builtin_amdgcn_s_setprio(1);                                          \
      _Pragma("unroll")                                                       \
      for (int dt = 0; dt < 8; ++dt) {                                        \
        bf16x8 vfr = *reinterpret_cast<const bf16x8*>(                        \
            pv[sub] + (cb) * (128 * 64) + dt * 1024);                         \
        o[0][dt] = __builtin_amdgcn_mfma_f32_16x16x32_bf16(                   \
            pa0, vfr, o[0][dt], 0, 0, 0);                                     \
        o[1][dt] = __builtin_amdgcn_mfma_f32_16x16x32_bf16(                   \
            pa1, vfr, o[1][dt], 0, 0, 0);                                     \
      }                                                                       \
      __builtin_amdgcn_s_setprio(0);                                          \
    } }

  AT_STAGE(0, 0);
  __syncthreads();
  #pragma unroll 1
  for (int it = 0; it < 32; it += 2) {
    AT_STAGE(1, it + 1);                       // prefetch while computing cur
    AT_COMPUTE(0);
    __syncthreads();                           // next chunk landed; buf0 free
    if (it + 2 < 32) AT_STAGE(0, it + 2);
    AT_COMPUTE(1);
    __syncthreads();
  }
#undef AT_STAGE
#undef AT_COMPUTE

  // epilogue: o[ng][dt][r] = O[nq + ng*16 + quad*4 + r][dt*16 + l15]
  #pragma unroll
  for (int ng = 0; ng < 2; ++ng)
    #pragma unroll
    for (int dt = 0; dt < 8; ++dt)
      #pragma unroll
      for (int r = 0; r < 4; ++r)
        out[((size_t)b * N_ + nq + ng * 16 + quad * 4 + r) * D_ + dt * 16 + l15] =
            o[ng][dt][r];
}

extern "C" void kernel_launch(void* const* d_in, const int* in_sizes, int n_in,
                              void* d_out, int out_size, void* d_ws, size_t ws_size,
                              hipStream_t stream) {
  const float* Q = (const float*)d_in[0];
  const float* K = (const float*)d_in[1];
  const float* V = (const float*)d_in[2];
  float* out = (float*)d_out;

  const size_t elems = (size_t)B_ * N_ * D_;   // 8,388,608 per tensor
  unsigned short* Qb = (unsigned short*)d_ws;                  // 16 MB
  unsigned short* Kb = Qb + elems;                             // 16 MB
  unsigned short* Vt = Kb + elems;                             // 16 MB
  float* colsum = (float*)(Vt + elems);                        // 256 KB
  // total ws use ~= 48.3 MB (proven safe)

  prep_kernel<<<18432, 256, 0, stream>>>(Q, K, V, Qb, Kb, Vt, colsum);
  colstats_v10_kernel<<<512, 256, 0, stream>>>(Qb, Kb, colsum);
  attn_v9_kernel<<<512, 256, 0, stream>>>(Qb, Kb, Vt, colsum, out);
}

// Round 8
// 276.660 us; speedup vs baseline: 1.1487x; 1.0227x over previous
//
#include <hip/hip_runtime.h>
#include <hip/hip_bf16.h>

#define B_  32
#define N_  2048
#define M_  2048
#define D_  128

typedef __attribute__((ext_vector_type(4)))  float f32x4;
typedef __attribute__((ext_vector_type(8)))  short bf16x8;

// log2(e) / sqrt(128): softmax in exp2 domain; folded into Q's bf16 cast.
static constexpr float SCALE2 = 1.4426950408889634f / 11.313708498984761f;

__device__ __forceinline__ unsigned short f2bf(float x) {
  union { float f; unsigned u; } c; c.f = x;
  unsigned u = c.u;
  return (unsigned short)((u + 0x7FFFu + ((u >> 16) & 1u)) >> 16);  // RNE
}

__device__ __forceinline__ unsigned pk2bf(float a, float b) {
  float2 f2; f2.x = a; f2.y = b;
  __hip_bfloat162 h = __float22bfloat162_rn(f2);   // v_cvt_pk_bf16_f32
  union { __hip_bfloat162 h; unsigned u; } c; c.h = h;
  return c.u;
}

__device__ __forceinline__ float fexp2(float x) {
#if __has_builtin(__builtin_amdgcn_exp2f)
  return __builtin_amdgcn_exp2f(x);
#else
  float r; asm("v_exp_f32 %0, %1" : "=v"(r) : "v"(x)); return r;
#endif
}
__device__ __forceinline__ float flog2(float x) {
#if __has_builtin(__builtin_amdgcn_logf)
  return __builtin_amdgcn_logf(x);
#else
  float r; asm("v_log_f32 %0, %1" : "=v"(r) : "v"(x)); return r;
#endif
}

// async global->LDS, 16B per lane; LDS dest = wave-uniform base + lane*16
__device__ __forceinline__ void gl2lds16(const void* gp, void* lp) {
  __builtin_amdgcn_global_load_lds(
      (const __attribute__((address_space(1))) unsigned int*)gp,
      (__attribute__((address_space(3))) unsigned int*)lp, 16, 0, 0);
}

// ---------- prep (one dispatch): V transpose FIRST, then cast Q (SCALE2),
// cast K, zero colsum. VERBATIM R3 (proven; part of the 238.7us best total).
// blocks [0,2048): V transpose; [2048,10240): Q cast; [10240,18432): K cast.
__global__ __launch_bounds__(256) void prep_kernel(
    const float* __restrict__ Q, const float* __restrict__ K,
    const float* __restrict__ V, unsigned short* __restrict__ Qb,
    unsigned short* __restrict__ Kb, unsigned short* __restrict__ Vt,
    float* __restrict__ colsum) {
  const int blk = blockIdx.x;
  if (blk >= 2048) {
    const bool isK = blk >= 10240;
    const int i = (isK ? blk - 10240 : blk - 2048) * 256 + threadIdx.x;
    if (!isK && blk - 2048 < 64) {
      const int j = (blk - 2048) * 256 + threadIdx.x;   // < 16384 == B_*M_/4
      reinterpret_cast<float4*>(colsum)[j] = make_float4(0.f, 0.f, 0.f, 0.f);
    }
    const float4* src = reinterpret_cast<const float4*>(isK ? K : Q);
    uint2* dst = reinterpret_cast<uint2*>(isK ? Kb : Qb);
    const float sc = isK ? 1.0f : SCALE2;
    const float4 v = src[i];
    uint2 o;
    o.x = pk2bf(v.x * sc, v.y * sc);
    o.y = pk2bf(v.z * sc, v.w * sc);
    dst[i] = o;
    return;
  }
  // V transpose: idx -> (b, m0, d0); 2048 blocks = (M/64=32) x (D/64=2) x (B=32)
  const int idx = blk;
  const int b  = idx >> 6;
  const int m0 = ((idx >> 1) & 31) * 64;
  const int d0 = (idx & 1) * 64;
  __shared__ float t[64][65];
  const int tid = threadIdx.x;
  const int r = tid >> 2;   // 0..63
  const int c = tid & 3;    // 0..3
  const float* src = V + ((size_t)b * M_ + (m0 + r)) * D_ + d0 + c * 16;
  #pragma unroll
  for (int i = 0; i < 4; ++i) {
    float4 v = reinterpret_cast<const float4*>(src)[i];
    t[r][c * 16 + i * 4 + 0] = v.x;
    t[r][c * 16 + i * 4 + 1] = v.y;
    t[r][c * 16 + i * 4 + 2] = v.z;
    t[r][c * 16 + i * 4 + 3] = v.w;
  }
  __syncthreads();
  ushort4 ob[4];
  #pragma unroll
  for (int i = 0; i < 4; ++i) {
    ob[i].x = f2bf(t[c * 16 + i * 4 + 0][r]);
    ob[i].y = f2bf(t[c * 16 + i * 4 + 1][r]);
    ob[i].z = f2bf(t[c * 16 + i * 4 + 2][r]);
    ob[i].w = f2bf(t[c * 16 + i * 4 + 3][r]);
  }
  ushort4* dst = reinterpret_cast<ushort4*>(
      Vt + ((size_t)b * D_ + d0 + r) * M_ + m0 + c * 16);
  #pragma unroll
  for (int i = 0; i < 4; ++i) dst[i] = ob[i];
}

// ---------- pass 1: colsum[b][m] += sum_{n in half} 2^(s2[n,m]-16) ----------
// VERBATIM v9 (R3-proven, ~65-80us at 4 blocks/CU — the 4-domain datapoint).
__global__ __launch_bounds__(256, 2) void colstats_v9_kernel(
    const unsigned short* __restrict__ Qb, const unsigned short* __restrict__ Kb,
    float* __restrict__ colsum) {
  const int id   = blockIdx.x;          // 0..1023
  const int x    = id >> 6;             // m-block 0..15
  const int q    = id & 63;
  const int b    = q >> 1;
  const int y    = q & 1;               // n-half
  const int lane = threadIdx.x & 63;
  const int l15  = lane & 15;
  const int quad = lane >> 4;
  const int mw   = x * 128 + (threadIdx.x >> 6) * 32;
  const int nbase = y * (N_ / 2);       // 1024-n stripe

  __shared__ unsigned short qbuf[2][64 * 128];  // 2 x 16 KB; rows n, chunk c^(n&15)

  bf16x8 kf[2][4];
  #pragma unroll
  for (int cg = 0; cg < 2; ++cg) {
    const unsigned short* Kr =
        Kb + ((size_t)b * M_ + mw + cg * 16 + l15) * D_ + quad * 8;
    #pragma unroll
    for (int kc = 0; kc < 4; ++kc)
      kf[cg][kc] = *reinterpret_cast<const bf16x8*>(Kr + kc * 32);
  }

  const unsigned short* pq[4];
  #pragma unroll
  for (int kc = 0; kc < 4; ++kc)
    pq[kc] = qbuf[0] + l15 * 128 + (((kc * 4 + quad) ^ l15) * 8);

  const unsigned short* qg[4];
  unsigned short* ql[4];
  #pragma unroll
  for (int i = 0; i < 4; ++i) {
    int s = i * 256 + threadIdx.x;             // 16B slot 0..1023
    int r = s >> 4, c = (s & 15) ^ (r & 15);
    qg[i] = Qb + ((size_t)b * N_ + nbase + r) * D_ + c * 8;
    ql[i] = qbuf[0] + (size_t)s * 8;           // s*16 bytes
  }

  float psum[2] = {0.f, 0.f};

#define CS_STAGE(nb)                                                          \
  { _Pragma("unroll")                                                         \
    for (int i = 0; i < 4; ++i) {                                             \
      gl2lds16(qg[i], ql[i] + (nb) * (64 * 128));                             \
      qg[i] += 64 * D_;                                                       \
    } }

#define CS_COMPUTE(cb)                                                        \
  { _Pragma("unroll")                                                         \
    for (int ng = 0; ng < 4; ++ng) {                                          \
      f32x4 acc[2] = {{0.f,0.f,0.f,0.f}, {0.f,0.f,0.f,0.f}};                  \
      __builtin_amdgcn_s_setprio(1);                                          \
      _Pragma("unroll")                                                       \
      for (int kc = 0; kc < 4; ++kc) {                                        \
        bf16x8 af = *reinterpret_cast<const bf16x8*>(                         \
            pq[kc] + (cb) * (64 * 128) + ng * 2048);                          \
        _Pragma("unroll")                                                     \
        for (int cg = 0; cg < 2; ++cg)                                        \
          acc[cg] = __builtin_amdgcn_mfma_f32_16x16x32_bf16(                  \
              af, kf[cg][kc], acc[cg], 0, 0, 0);                              \
      }                                                                       \
      __builtin_amdgcn_s_setprio(0);                                          \
      _Pragma("unroll")                                                       \
      for (int cg = 0; cg < 2; ++cg)                                          \
        psum[cg] += fexp2(acc[cg][0] - 16.f) + fexp2(acc[cg][1] - 16.f) +     \
                    fexp2(acc[cg][2] - 16.f) + fexp2(acc[cg][3] - 16.f);      \
    } }

  CS_STAGE(0);                                 // chunk 0
  __syncthreads();
  #pragma unroll 1
  for (int it = 0; it < 16; it += 2) {
    CS_STAGE(1);                               // chunk it+1 (<=15 always)
    CS_COMPUTE(0);
    __syncthreads();                           // chunk it+1 landed; buf0 free
    if (it + 2 < 16) CS_STAGE(0);              // chunk it+2
    CS_COMPUTE(1);
    __syncthreads();
  }
#undef CS_STAGE
#undef CS_COMPUTE

  #pragma unroll
  for (int cg = 0; cg < 2; ++cg) {
    psum[cg] += __shfl_xor(psum[cg], 16);
    psum[cg] += __shfl_xor(psum[cg], 32);
  }
  if (quad == 0) {
    #pragma unroll
    for (int cg = 0; cg < 2; ++cg)
      atomicAdd(colsum + (size_t)b * M_ + mw + cg * 16 + l15, psum[cg]);
  }
}

// ---------- pass 2: O[n,d] = sum_m 2^(s2[n,m]-cml[m]) * Vt[d,m] ----------
// v12: attack the ~88us barrier-latency wall (R7: colstats_v10 with HALF of
// attn's work = same 88us at same 2-blocks/CU structure; colstats_v9 at 4/CU
// beats its 2/CU clone). 1024 blocks x 128 threads (2 waves), 32-m chunks,
// LDS 33KB/block -> 4 INDEPENDENT barrier domains per CU (was 2). Wave-level
// MFMA shapes identical to v9. P LDS round-trip (pbuf, 3.1M bank conflicts,
// 2 lgkm stalls/sub) replaced by in-register shuffle: each lane packs its 8
// exp-weights into 4 u32 (as before), then 16 shfl + 8 selects rebuild the
// PV A-frags. Mapping: dest lane (q,l15) word j-pair (2w,2w+1) comes from
// src lane ((q&1)*32 + (w>=2)*16 + l15), cg-selected by q>=2.
__global__ __launch_bounds__(128, 2) void attn_v12_kernel(
    const unsigned short* __restrict__ Qb, const unsigned short* __restrict__ Kb,
    const unsigned short* __restrict__ Vt, const float* __restrict__ colsum,
    float* __restrict__ out) {
  const int id   = blockIdx.x;        // 0..1023
  const int b    = id & 31;           // id%8 == b%8: XCD swizzle preserved
  const int xq   = id >> 5;           // n-block 0..31 (64 n each)
  const int wv   = threadIdx.x >> 6;  // 0..1
  const int lane = threadIdx.x & 63;
  const int l15  = lane & 15;
  const int quad = lane >> 4;
  const int nq   = xq * 64 + wv * 32;

  __shared__ unsigned short kbuf[2][32 * 128];  // 2x8 KB: rows m (256B), chunk c^(m&15)
  __shared__ unsigned short vbuf[2][128 * 32];  // 2x8 KB: rows d (64B), chunk c^(d&3)
  __shared__ float cmlb[2][32];                 // per-chunk log2 column denominators

  // Q B-operand: B[col=n=ng*16+l15][k=quad*8+j (+kc*32)] — loop invariant
  bf16x8 qf[2][4];
  #pragma unroll
  for (int ng = 0; ng < 2; ++ng) {
    const unsigned short* Qr =
        Qb + ((size_t)b * N_ + nq + ng * 16 + l15) * D_ + quad * 8;
    #pragma unroll
    for (int kc = 0; kc < 4; ++kc)
      qf[ng][kc] = *reinterpret_cast<const bf16x8*>(Qr + kc * 32);
  }

  // hoisted LDS bases (u16 units)
  const unsigned short* pk[4];   // K read: + cb*4096 + cg*2048
  #pragma unroll
  for (int kc = 0; kc < 4; ++kc)
    pk[kc] = kbuf[0] + l15 * 128 + (((kc * 4 + quad) ^ l15) * 8);
  const unsigned short* pv =     // V read: + cb*4096 + dt*512
      vbuf[0] + l15 * 32 + ((quad ^ (l15 & 3)) * 8);

  // running DMA source ptrs (4 K + 4 V slots per thread), constant LDS dests
  const unsigned short* kg[4]; unsigned short* kl[4];
  const unsigned short* vg[4]; unsigned short* vl[4];
  #pragma unroll
  for (int i = 0; i < 4; ++i) {
    int s = i * 128 + threadIdx.x;               // 16B slot 0..511
    int rk = s >> 4, ck = (s & 15) ^ (rk & 15);  // K rows 0..31, 16 chunks
    kg[i] = Kb + ((size_t)b * M_ + rk) * D_ + ck * 8;
    kl[i] = kbuf[0] + (size_t)s * 8;
    int rv = s >> 2, cv = (s & 3) ^ (rv & 3);    // V rows 0..127, 4 chunks
    vg[i] = Vt + ((size_t)b * D_ + rv) * M_ + cv * 8;
    vl[i] = vbuf[0] + (size_t)s * 8;
  }

  const float* csb = colsum + (size_t)b * M_;
  const int srcA = (quad & 1) * 32 + l15;      // shuffle sources (per ng)
  const int srcB = srcA + 16;
  const bool hi  = quad >= 2;                  // cg select

  f32x4 o[2][8];
  #pragma unroll
  for (int ng = 0; ng < 2; ++ng)
    #pragma unroll
    for (int dt = 0; dt < 8; ++dt) o[ng][dt] = (f32x4){0.f, 0.f, 0.f, 0.f};

#define AT_STAGE(nb, chunk)                                                   \
  { _Pragma("unroll")                                                         \
    for (int i = 0; i < 4; ++i) {                                             \
      gl2lds16(kg[i], kl[i] + (nb) * (32 * 128));                             \
      kg[i] += 32 * D_;                                                       \
      gl2lds16(vg[i], vl[i] + (nb) * (128 * 32));                             \
      vg[i] += 32;                                                            \
    }                                                                         \
    if (threadIdx.x < 32)                                                     \
      cmlb[nb][threadIdx.x] =                                                 \
          flog2(csb[(chunk) * 32 + threadIdx.x]) + 16.f; }

#define AT_COMPUTE(cb)                                                        \
  {                                                                           \
    /* QK^T (S^T): sacc[cg][ng]: row m32=cg*16+quad*4+r, col n=ng*16+l15 */   \
    f32x4 sacc[2][2] = {{{0.f,0.f,0.f,0.f},{0.f,0.f,0.f,0.f}},                \
                        {{0.f,0.f,0.f,0.f},{0.f,0.f,0.f,0.f}}};               \
    __builtin_amdgcn_s_setprio(1);                                            \
    _Pragma("unroll")                                                         \
    for (int kc = 0; kc < 4; ++kc) {                                          \
      _Pragma("unroll")                                                       \
      for (int cg = 0; cg < 2; ++cg) {                                        \
        bf16x8 kfr = *reinterpret_cast<const bf16x8*>(                        \
            pk[kc] + (cb) * (32 * 128) + cg * 2048);                          \
        sacc[cg][0] = __builtin_amdgcn_mfma_f32_16x16x32_bf16(                \
            kfr, qf[0][kc], sacc[cg][0], 0, 0, 0);                            \
        sacc[cg][1] = __builtin_amdgcn_mfma_f32_16x16x32_bf16(                \
            kfr, qf[1][kc], sacc[cg][1], 0, 0, 0);                            \
      }                                                                       \
    }                                                                         \
    __builtin_amdgcn_s_setprio(0);                                            \
    /* normalized weights, packed: w01/w23 per (cg,ng) — same pk2bf as v9 */  \
    unsigned w01[2][2], w23[2][2];                                            \
    _Pragma("unroll")                                                         \
    for (int cg = 0; cg < 2; ++cg) {                                          \
      float4 cm4 = *reinterpret_cast<const float4*>(                          \
          &cmlb[cb][cg * 16 + quad * 4]);                                     \
      _Pragma("unroll")                                                       \
      for (int ng = 0; ng < 2; ++ng) {                                        \
        w01[cg][ng] = pk2bf(fexp2(sacc[cg][ng][0] - cm4.x),                   \
                            fexp2(sacc[cg][ng][1] - cm4.y));                  \
        w23[cg][ng] = pk2bf(fexp2(sacc[cg][ng][2] - cm4.z),                   \
                            fexp2(sacc[cg][ng][3] - cm4.w));                  \
      }                                                                       \
    }                                                                         \
    /* in-register P transpose: build PV A-frags via wave shuffles */         \
    bf16x8 pa[2];                                                             \
    _Pragma("unroll")                                                         \
    for (int ng = 0; ng < 2; ++ng) {                                          \
      unsigned a0 = __shfl(w01[0][ng], srcA), a1 = __shfl(w01[1][ng], srcA);  \
      unsigned b0 = __shfl(w23[0][ng], srcA), b1 = __shfl(w23[1][ng], srcA);  \
      unsigned c0 = __shfl(w01[0][ng], srcB), c1 = __shfl(w01[1][ng], srcB);  \
      unsigned d0 = __shfl(w23[0][ng], srcB), d1 = __shfl(w23[1][ng], srcB);  \
      union { bf16x8 v; unsigned u[4]; } pu;                                  \
      pu.u[0] = hi ? a1 : a0;                                                 \
      pu.u[1] = hi ? b1 : b0;                                                 \
      pu.u[2] = hi ? c1 : c0;                                                 \
      pu.u[3] = hi ? d1 : d0;                                                 \
      pa[ng] = pu.v;                                                          \
    }                                                                         \
    /* PV: o[ng][dt] += pa[ng] x V-frag */                                    \
    __builtin_amdgcn_s_setprio(1);                                            \
    _Pragma("unroll")                                                         \
    for (int dt = 0; dt < 8; ++dt) {                                          \
      bf16x8 vfr = *reinterpret_cast<const bf16x8*>(                          \
          pv + (cb) * (128 * 32) + dt * 512);                                 \
      o[0][dt] = __builtin_amdgcn_mfma_f32_16x16x32_bf16(                     \
          pa[0], vfr, o[0][dt], 0, 0, 0);                                     \
      o[1][dt] = __builtin_amdgcn_mfma_f32_16x16x32_bf16(                     \
          pa[1], vfr, o[1][dt], 0, 0, 0);                                     \
    }                                                                         \
    __builtin_amdgcn_s_setprio(0);                                            \
  }

  AT_STAGE(0, 0);
  __syncthreads();
  #pragma unroll 1
  for (int it = 0; it < 64; it += 2) {
    AT_STAGE(1, it + 1);                       // prefetch while computing cur
    AT_COMPUTE(0);
    __syncthreads();                           // next chunk landed; buf0 free
    if (it + 2 < 64) AT_STAGE(0, it + 2);
    AT_COMPUTE(1);
    __syncthreads();
  }
#undef AT_STAGE
#undef AT_COMPUTE

  // epilogue: o[ng][dt][r] = O[nq + ng*16 + quad*4 + r][dt*16 + l15]
  #pragma unroll
  for (int ng = 0; ng < 2; ++ng)
    #pragma unroll
    for (int dt = 0; dt < 8; ++dt)
      #pragma unroll
      for (int r = 0; r < 4; ++r)
        out[((size_t)b * N_ + nq + ng * 16 + quad * 4 + r) * D_ + dt * 16 + l15] =
            o[ng][dt][r];
}

extern "C" void kernel_launch(void* const* d_in, const int* in_sizes, int n_in,
                              void* d_out, int out_size, void* d_ws, size_t ws_size,
                              hipStream_t stream) {
  const float* Q = (const float*)d_in[0];
  const float* K = (const float*)d_in[1];
  const float* V = (const float*)d_in[2];
  float* out = (float*)d_out;

  const size_t elems = (size_t)B_ * N_ * D_;   // 8,388,608 per tensor
  unsigned short* Qb = (unsigned short*)d_ws;                  // 16 MB
  unsigned short* Kb = Qb + elems;                             // 16 MB
  unsigned short* Vt = Kb + elems;                             // 16 MB
  float* colsum = (float*)(Vt + elems);                        // 256 KB
  // total ws use ~= 48.3 MB (proven safe)

  prep_kernel<<<18432, 256, 0, stream>>>(Q, K, V, Qb, Kb, Vt, colsum);
  colstats_v9_kernel<<<1024, 256, 0, stream>>>(Qb, Kb, colsum);
  attn_v12_kernel<<<1024, 128, 0, stream>>>(Qb, Kb, Vt, colsum, out);
}

// Round 9
// 265.759 us; speedup vs baseline: 1.1958x; 1.0410x over previous
//
#include <hip/hip_runtime.h>
#include <hip/hip_bf16.h>

#define B_  32
#define N_  2048
#define M_  2048
#define D_  128

typedef __attribute__((ext_vector_type(4)))  float f32x4;
typedef __attribute__((ext_vector_type(8)))  short bf16x8;

// log2(e) / sqrt(128): softmax in exp2 domain; folded into Q's bf16 cast.
static constexpr float SCALE2 = 1.4426950408889634f / 11.313708498984761f;

__device__ __forceinline__ unsigned short f2bf(float x) {
  union { float f; unsigned u; } c; c.f = x;
  unsigned u = c.u;
  return (unsigned short)((u + 0x7FFFu + ((u >> 16) & 1u)) >> 16);  // RNE
}

__device__ __forceinline__ unsigned pk2bf(float a, float b) {
  float2 f2; f2.x = a; f2.y = b;
  __hip_bfloat162 h = __float22bfloat162_rn(f2);   // v_cvt_pk_bf16_f32
  union { __hip_bfloat162 h; unsigned u; } c; c.h = h;
  return c.u;
}

__device__ __forceinline__ float fexp2(float x) {
#if __has_builtin(__builtin_amdgcn_exp2f)
  return __builtin_amdgcn_exp2f(x);
#else
  float r; asm("v_exp_f32 %0, %1" : "=v"(r) : "v"(x)); return r;
#endif
}
__device__ __forceinline__ float flog2(float x) {
#if __has_builtin(__builtin_amdgcn_logf)
  return __builtin_amdgcn_logf(x);
#else
  float r; asm("v_log_f32 %0, %1" : "=v"(r) : "v"(x)); return r;
#endif
}

// async global->LDS, 16B per lane; LDS dest = wave-uniform base + lane*16
__device__ __forceinline__ void gl2lds16(const void* gp, void* lp) {
  __builtin_amdgcn_global_load_lds(
      (const __attribute__((address_space(1))) unsigned int*)gp,
      (__attribute__((address_space(3))) unsigned int*)lp, 16, 0, 0);
}

// counted-vmcnt sync: certify everything except the N newest VMEM groups,
// then raw barrier (does NOT drain counters — the whole point; T3/T4).
// memory-clobber asm fences LDS reads/DMA issues across the sync.
#define SYNC_VM(N)                                                            \
  asm volatile("s_waitcnt vmcnt(" #N ")" ::: "memory");                       \
  __builtin_amdgcn_s_barrier();                                               \
  asm volatile("" ::: "memory");

// ---------- prep (one dispatch): V transpose FIRST, then cast Q (SCALE2),
// cast K, zero colsum. VERBATIM R3 (proven; part of the 238.7us best total).
__global__ __launch_bounds__(256) void prep_kernel(
    const float* __restrict__ Q, const float* __restrict__ K,
    const float* __restrict__ V, unsigned short* __restrict__ Qb,
    unsigned short* __restrict__ Kb, unsigned short* __restrict__ Vt,
    float* __restrict__ colsum) {
  const int blk = blockIdx.x;
  if (blk >= 2048) {
    const bool isK = blk >= 10240;
    const int i = (isK ? blk - 10240 : blk - 2048) * 256 + threadIdx.x;
    if (!isK && blk - 2048 < 64) {
      const int j = (blk - 2048) * 256 + threadIdx.x;   // < 16384 == B_*M_/4
      reinterpret_cast<float4*>(colsum)[j] = make_float4(0.f, 0.f, 0.f, 0.f);
    }
    const float4* src = reinterpret_cast<const float4*>(isK ? K : Q);
    uint2* dst = reinterpret_cast<uint2*>(isK ? Kb : Qb);
    const float sc = isK ? 1.0f : SCALE2;
    const float4 v = src[i];
    uint2 o;
    o.x = pk2bf(v.x * sc, v.y * sc);
    o.y = pk2bf(v.z * sc, v.w * sc);
    dst[i] = o;
    return;
  }
  const int idx = blk;
  const int b  = idx >> 6;
  const int m0 = ((idx >> 1) & 31) * 64;
  const int d0 = (idx & 1) * 64;
  __shared__ float t[64][65];
  const int tid = threadIdx.x;
  const int r = tid >> 2;   // 0..63
  const int c = tid & 3;    // 0..3
  const float* src = V + ((size_t)b * M_ + (m0 + r)) * D_ + d0 + c * 16;
  #pragma unroll
  for (int i = 0; i < 4; ++i) {
    float4 v = reinterpret_cast<const float4*>(src)[i];
    t[r][c * 16 + i * 4 + 0] = v.x;
    t[r][c * 16 + i * 4 + 1] = v.y;
    t[r][c * 16 + i * 4 + 2] = v.z;
    t[r][c * 16 + i * 4 + 3] = v.w;
  }
  __syncthreads();
  ushort4 ob[4];
  #pragma unroll
  for (int i = 0; i < 4; ++i) {
    ob[i].x = f2bf(t[c * 16 + i * 4 + 0][r]);
    ob[i].y = f2bf(t[c * 16 + i * 4 + 1][r]);
    ob[i].z = f2bf(t[c * 16 + i * 4 + 2][r]);
    ob[i].w = f2bf(t[c * 16 + i * 4 + 3][r]);
  }
  ushort4* dst = reinterpret_cast<ushort4*>(
      Vt + ((size_t)b * D_ + d0 + r) * M_ + m0 + c * 16);
  #pragma unroll
  for (int i = 0; i < 4; ++i) dst[i] = ob[i];
}

// ---------- pass 1: colsum[b][m] += sum_{n in half} 2^(s2[n,m]-16) ----------
// v13 = v9 layout/math verbatim, but counted-vmcnt pipeline: each 64-n tile
// split into SA (rows 0..31, DMA slots 0,1) / SB (rows 32..63, slots 2,3);
// stage SB(t+1) at sync1, SA(t+2) at sync2; waits vmcnt(4) = two newest
// 2-DMA groups allowed in flight -> oldest group certified. Never drains to 0.
__global__ __launch_bounds__(256, 2) void colstats_v13_kernel(
    const unsigned short* __restrict__ Qb, const unsigned short* __restrict__ Kb,
    float* __restrict__ colsum) {
  const int id   = blockIdx.x;          // 0..1023
  const int x    = id >> 6;             // m-block 0..15
  const int q    = id & 63;
  const int b    = q >> 1;
  const int y    = q & 1;               // n-half
  const int lane = threadIdx.x & 63;
  const int l15  = lane & 15;
  const int quad = lane >> 4;
  const int mw   = x * 128 + (threadIdx.x >> 6) * 32;
  const int nbase = y * (N_ / 2);       // 1024-n stripe

  __shared__ unsigned short qbuf[2][64 * 128];  // 2 x 16 KB; rows n, chunk c^(n&15)

  bf16x8 kf[2][4];
  #pragma unroll
  for (int cg = 0; cg < 2; ++cg) {
    const unsigned short* Kr =
        Kb + ((size_t)b * M_ + mw + cg * 16 + l15) * D_ + quad * 8;
    #pragma unroll
    for (int kc = 0; kc < 4; ++kc)
      kf[cg][kc] = *reinterpret_cast<const bf16x8*>(Kr + kc * 32);
  }

  const unsigned short* pq[4];
  #pragma unroll
  for (int kc = 0; kc < 4; ++kc)
    pq[kc] = qbuf[0] + l15 * 128 + (((kc * 4 + quad) ^ l15) * 8);

  const unsigned short* qg[4];
  unsigned short* ql[4];
  #pragma unroll
  for (int i = 0; i < 4; ++i) {
    int s = i * 256 + threadIdx.x;             // 16B slot 0..1023
    int r = s >> 4, c = (s & 15) ^ (r & 15);
    qg[i] = Qb + ((size_t)b * N_ + nbase + r) * D_ + c * 8;
    ql[i] = qbuf[0] + (size_t)s * 8;           // s*16 bytes
  }

  float psum[2] = {0.f, 0.f};

#define CSA(nb)                                                               \
  { gl2lds16(qg[0], ql[0] + (nb) * (64 * 128)); qg[0] += 64 * D_;             \
    gl2lds16(qg[1], ql[1] + (nb) * (64 * 128)); qg[1] += 64 * D_; }
#define CSB(nb)                                                               \
  { gl2lds16(qg[2], ql[2] + (nb) * (64 * 128)); qg[2] += 64 * D_;             \
    gl2lds16(qg[3], ql[3] + (nb) * (64 * 128)); qg[3] += 64 * D_; }

#define CCG(cb, ng0)                                                          \
  { _Pragma("unroll")                                                         \
    for (int g = 0; g < 2; ++g) {                                             \
      const int ng = (ng0) + g;                                               \
      f32x4 acc[2] = {{0.f,0.f,0.f,0.f}, {0.f,0.f,0.f,0.f}};                  \
      __builtin_amdgcn_s_setprio(1);                                          \
      _Pragma("unroll")                                                       \
      for (int kc = 0; kc < 4; ++kc) {                                        \
        bf16x8 af = *reinterpret_cast<const bf16x8*>(                         \
            pq[kc] + (cb) * (64 * 128) + ng * 2048);                          \
        _Pragma("unroll")                                                     \
        for (int cg = 0; cg < 2; ++cg)                                        \
          acc[cg] = __builtin_amdgcn_mfma_f32_16x16x32_bf16(                  \
              af, kf[cg][kc], acc[cg], 0, 0, 0);                              \
      }                                                                       \
      __builtin_amdgcn_s_setprio(0);                                          \
      _Pragma("unroll")                                                       \
      for (int cg = 0; cg < 2; ++cg)                                          \
        psum[cg] += fexp2(acc[cg][0] - 16.f) + fexp2(acc[cg][1] - 16.f) +     \
                    fexp2(acc[cg][2] - 16.f) + fexp2(acc[cg][3] - 16.f);      \
    } }

  CSA(0); CSB(0); CSA(1);                      // prologue: 6 in flight
  #pragma unroll 1
  for (int it = 0; it < 16; it += 2) {
    SYNC_VM(4); CSB(1);                 CCG(0, 0);   // tile it   (buf0) rows 0..31
    SYNC_VM(4); if (it + 2 < 16) CSA(0); CCG(0, 2);  //                 rows 32..63
    SYNC_VM(4); if (it + 2 < 16) CSB(0); CCG(1, 0);  // tile it+1 (buf1)
    SYNC_VM(4); if (it + 3 < 16) CSA(1); CCG(1, 2);
  }
#undef CSA
#undef CSB
#undef CCG

  #pragma unroll
  for (int cg = 0; cg < 2; ++cg) {
    psum[cg] += __shfl_xor(psum[cg], 16);
    psum[cg] += __shfl_xor(psum[cg], 32);
  }
  if (quad == 0) {
    #pragma unroll
    for (int cg = 0; cg < 2; ++cg)
      atomicAdd(colsum + (size_t)b * M_ + mw + cg * 16 + l15, psum[cg]);
  }
}

// ---------- pass 2: O[n,d] = sum_m 2^(s2[n,m]-cml[m]) * Vt[d,m] ----------
// v13: v9 tile geometry/swizzles/occupancy verbatim; counted-vmcnt pipeline.
// Per 64-m tile: PH1 = QK^T + softmax (reads K + colsum), PH2 = PV (reads V).
// Stage groups per wave: SK = 4 K-DMA + 1 colsum-DMA (lane<16) = 5 vmem;
// SV = 4 V-DMA. Syncs wait vmcnt(9) = the two newest groups -> oldest
// certified; loads span ~1.5 tiles, never drained to 0. P now carried in
// REGISTERS (v12's HW-verified shuffle transpose) -> pbuf + its 3.1M bank
// conflicts deleted. colsum staged raw; flog2 applied at use (same values
// as v9's precomputed cml -> identical numerics).
__global__ __launch_bounds__(256, 2) void attn_v13_kernel(
    const unsigned short* __restrict__ Qb, const unsigned short* __restrict__ Kb,
    const unsigned short* __restrict__ Vt, const float* __restrict__ colsum,
    float* __restrict__ out) {
  const int id   = blockIdx.x;        // 0..511
  const int b    = id & 31;           // id%8==b%8: XCD swizzle
  const int xq   = id >> 5;           // n-block 0..15
  const int wv   = threadIdx.x >> 6;  // 0..3
  const int lane = threadIdx.x & 63;
  const int l15  = lane & 15;
  const int quad = lane >> 4;
  const int nq   = xq * 128 + wv * 32;

  __shared__ unsigned short kbuf[2][64 * 128];  // 2x16 KB: rows m (256B), chunk c^(m&15)
  __shared__ unsigned short vbuf[2][128 * 64];  // 2x16 KB: rows d (128B), chunk c^(d&7)
  __shared__ float csl[2][64];                  // raw colsum per tile (DMA-staged)

  // Q B-operand: B[col=n=ng*16+l15][k=quad*8+j (+kc*32)] — loop invariant
  bf16x8 qf[2][4];
  #pragma unroll
  for (int ng = 0; ng < 2; ++ng) {
    const unsigned short* Qr =
        Qb + ((size_t)b * N_ + nq + ng * 16 + l15) * D_ + quad * 8;
    #pragma unroll
    for (int kc = 0; kc < 4; ++kc)
      qf[ng][kc] = *reinterpret_cast<const bf16x8*>(Qr + kc * 32);
  }

  // hoisted LDS bases (u16 units) — v9 verbatim
  const unsigned short* pk[4];   // K read: + cb*8192 + sub*4096 + cg*2048
  #pragma unroll
  for (int kc = 0; kc < 4; ++kc)
    pk[kc] = kbuf[0] + l15 * 128 + (((kc * 4 + quad) ^ l15) * 8);
  const unsigned short* pv[2];   // V read: + cb*8192 + dt*1024
  #pragma unroll
  for (int sub = 0; sub < 2; ++sub)
    pv[sub] = vbuf[0] + l15 * 64 + (((sub * 4 + quad) ^ (l15 & 7)) * 8);

  // running DMA source ptrs (4 K + 4 V slots/thread + colsum), const LDS dests
  const unsigned short* kg[4]; unsigned short* kl[4];
  const unsigned short* vg[4]; unsigned short* vl[4];
  #pragma unroll
  for (int i = 0; i < 4; ++i) {
    int s = i * 256 + threadIdx.x;               // 16B slot 0..1023
    int rk = s >> 4, ck = (s & 15) ^ (rk & 15);
    kg[i] = Kb + ((size_t)b * M_ + rk) * D_ + ck * 8;
    kl[i] = kbuf[0] + (size_t)s * 8;
    int rv = s >> 3, cv = (s & 7) ^ (rv & 7);
    vg[i] = Vt + ((size_t)b * D_ + rv) * M_ + cv * 8;
    vl[i] = vbuf[0] + (size_t)s * 8;
  }
  const float* cmg = colsum + (size_t)b * M_ + (lane & 15) * 4;

  // shuffle-transpose constants (v12, HW-verified)
  const int srcA = (quad & 1) * 32 + l15;
  const int srcB = srcA + 16;
  const bool hi  = quad >= 2;

  bf16x8 pa[2][2];   // P A-frags carried PH1 -> PH2 (static indices only)
  f32x4 o[2][8];
  #pragma unroll
  for (int ng = 0; ng < 2; ++ng)
    #pragma unroll
    for (int dt = 0; dt < 8; ++dt) o[ng][dt] = (f32x4){0.f, 0.f, 0.f, 0.f};

#define AT_SK(nb)                                                             \
  { _Pragma("unroll")                                                         \
    for (int i = 0; i < 4; ++i) {                                             \
      gl2lds16(kg[i], kl[i] + (nb) * (64 * 128));                             \
      kg[i] += 64 * D_;                                                       \
    }                                                                         \
    if (lane < 16) gl2lds16(cmg, &csl[nb][(lane & 15) * 4]);                  \
    cmg += 64; }

#define AT_SV(nb)                                                             \
  { _Pragma("unroll")                                                         \
    for (int i = 0; i < 4; ++i) {                                             \
      gl2lds16(vg[i], vl[i] + (nb) * (128 * 64));                             \
      vg[i] += 64;                                                            \
    } }

#define AT_PH1(cb)                                                            \
  { _Pragma("unroll")                                                         \
    for (int sub = 0; sub < 2; ++sub) {                                       \
      f32x4 sacc[2][2] = {{{0.f,0.f,0.f,0.f},{0.f,0.f,0.f,0.f}},              \
                          {{0.f,0.f,0.f,0.f},{0.f,0.f,0.f,0.f}}};             \
      __builtin_amdgcn_s_setprio(1);                                          \
      _Pragma("unroll")                                                       \
      for (int kc = 0; kc < 4; ++kc) {                                        \
        _Pragma("unroll")                                                     \
        for (int cg = 0; cg < 2; ++cg) {                                      \
          bf16x8 kfr = *reinterpret_cast<const bf16x8*>(                      \
              pk[kc] + (cb) * (64 * 128) + sub * 4096 + cg * 2048);           \
          sacc[cg][0] = __builtin_amdgcn_mfma_f32_16x16x32_bf16(              \
              kfr, qf[0][kc], sacc[cg][0], 0, 0, 0);                          \
          sacc[cg][1] = __builtin_amdgcn_mfma_f32_16x16x32_bf16(              \
              kfr, qf[1][kc], sacc[cg][1], 0, 0, 0);                          \
        }                                                                     \
      }                                                                       \
      __builtin_amdgcn_s_setprio(0);                                          \
      /* cml = log2(colsum)+16, computed at use (same values as v9) */        \
      float4 cs0 = *reinterpret_cast<const float4*>(                          \
          &csl[cb][sub * 32 + quad * 4]);                                     \
      float4 cs1 = *reinterpret_cast<const float4*>(                          \
          &csl[cb][sub * 32 + 16 + quad * 4]);                                \
      float4 cm0, cm1;                                                        \
      cm0.x = flog2(cs0.x) + 16.f; cm0.y = flog2(cs0.y) + 16.f;               \
      cm0.z = flog2(cs0.z) + 16.f; cm0.w = flog2(cs0.w) + 16.f;               \
      cm1.x = flog2(cs1.x) + 16.f; cm1.y = flog2(cs1.y) + 16.f;               \
      cm1.z = flog2(cs1.z) + 16.f; cm1.w = flog2(cs1.w) + 16.f;               \
      unsigned w01[2][2], w23[2][2];                                          \
      _Pragma("unroll")                                                       \
      for (int ng = 0; ng < 2; ++ng) {                                        \
        w01[0][ng] = pk2bf(fexp2(sacc[0][ng][0] - cm0.x),                     \
                           fexp2(sacc[0][ng][1] - cm0.y));                    \
        w23[0][ng] = pk2bf(fexp2(sacc[0][ng][2] - cm0.z),                     \
                           fexp2(sacc[0][ng][3] - cm0.w));                    \
        w01[1][ng] = pk2bf(fexp2(sacc[1][ng][0] - cm1.x),                     \
                           fexp2(sacc[1][ng][1] - cm1.y));                    \
        w23[1][ng] = pk2bf(fexp2(sacc[1][ng][2] - cm1.z),                     \
                           fexp2(sacc[1][ng][3] - cm1.w));                    \
      }                                                                       \
      /* in-register P transpose (v12-verified mapping) */                    \
      _Pragma("unroll")                                                       \
      for (int ng = 0; ng < 2; ++ng) {                                        \
        unsigned a0 = __shfl(w01[0][ng], srcA), a1 = __shfl(w01[1][ng], srcA);\
        unsigned b0 = __shfl(w23[0][ng], srcA), b1 = __shfl(w23[1][ng], srcA);\
        unsigned c0 = __shfl(w01[0][ng], srcB), c1 = __shfl(w01[1][ng], srcB);\
        unsigned d0 = __shfl(w23[0][ng], srcB), d1 = __shfl(w23[1][ng], srcB);\
        union { bf16x8 v; unsigned u[4]; } pu;                                \
        pu.u[0] = hi ? a1 : a0;                                               \
        pu.u[1] = hi ? b1 : b0;                                               \
        pu.u[2] = hi ? c1 : c0;                                               \
        pu.u[3] = hi ? d1 : d0;                                               \
        pa[sub][ng] = pu.v;                                                   \
      }                                                                       \
    } }

#define AT_PH2(cb)                                                            \
  { __builtin_amdgcn_s_setprio(1);                                            \
    _Pragma("unroll")                                                         \
    for (int sub = 0; sub < 2; ++sub)                                         \
      _Pragma("unroll")                                                       \
      for (int dt = 0; dt < 8; ++dt) {                                        \
        bf16x8 vfr = *reinterpret_cast<const bf16x8*>(                        \
            pv[sub] + (cb) * (128 * 64) + dt * 1024);                         \
        o[0][dt] = __builtin_amdgcn_mfma_f32_16x16x32_bf16(                   \
            pa[sub][0], vfr, o[0][dt], 0, 0, 0);                              \
        o[1][dt] = __builtin_amdgcn_mfma_f32_16x16x32_bf16(                   \
            pa[sub][1], vfr, o[1][dt], 0, 0, 0);                              \
      }                                                                       \
    __builtin_amdgcn_s_setprio(0); }

  AT_SK(0); AT_SV(0); AT_SK(1);                // prologue: 14 vmem in flight
  #pragma unroll 1
  for (int it = 0; it < 32; it += 2) {
    SYNC_VM(9); AT_SV(1);                 AT_PH1(0);   // tile it   (buf0)
    SYNC_VM(9); if (it + 2 < 32) AT_SK(0); AT_PH2(0);
    SYNC_VM(9); if (it + 2 < 32) AT_SV(0); AT_PH1(1);  // tile it+1 (buf1)
    SYNC_VM(9); if (it + 3 < 32) AT_SK(1); AT_PH2(1);
  }
#undef AT_SK
#undef AT_SV
#undef AT_PH1
#undef AT_PH2

  // epilogue: o[ng][dt][r] = O[nq + ng*16 + quad*4 + r][dt*16 + l15]
  #pragma unroll
  for (int ng = 0; ng < 2; ++ng)
    #pragma unroll
    for (int dt = 0; dt < 8; ++dt)
      #pragma unroll
      for (int r = 0; r < 4; ++r)
        out[((size_t)b * N_ + nq + ng * 16 + quad * 4 + r) * D_ + dt * 16 + l15] =
            o[ng][dt][r];
}

extern "C" void kernel_launch(void* const* d_in, const int* in_sizes, int n_in,
                              void* d_out, int out_size, void* d_ws, size_t ws_size,
                              hipStream_t stream) {
  const float* Q = (const float*)d_in[0];
  const float* K = (const float*)d_in[1];
  const float* V = (const float*)d_in[2];
  float* out = (float*)d_out;

  const size_t elems = (size_t)B_ * N_ * D_;   // 8,388,608 per tensor
  unsigned short* Qb = (unsigned short*)d_ws;                  // 16 MB
  unsigned short* Kb = Qb + elems;                             // 16 MB
  unsigned short* Vt = Kb + elems;                             // 16 MB
  float* colsum = (float*)(Vt + elems);                        // 256 KB
  // total ws use ~= 48.3 MB (proven safe)

  prep_kernel<<<18432, 256, 0, stream>>>(Q, K, V, Qb, Kb, Vt, colsum);
  colstats_v13_kernel<<<1024, 256, 0, stream>>>(Qb, Kb, colsum);
  attn_v13_kernel<<<512, 256, 0, stream>>>(Qb, Kb, Vt, colsum, out);
}